// Round 6
// baseline (460.684 us; speedup 1.0000x reference)
//
#include <hip/hip_runtime.h>
#include <cstdint>
#include <cstddef>

// Problem constants
#define M_DIM 8192
#define N_DIM 4096
#define K_DIM 4096

#define BM 128
#define BN 128
#define BK 64   // int8 elements per K-step (64 bytes per LDS row)

using i32x4 = __attribute__((ext_vector_type(4))) int;

__device__ __forceinline__ void async_load16(const void* g, void* l) {
    __builtin_amdgcn_global_load_lds(
        (const __attribute__((address_space(1))) void*)g,
        (__attribute__((address_space(3))) void*)l,
        16, 0, 0);
}

// Pack int32 values (range [-128,127]) to int8 for BOTH x and w in one dispatch.
__global__ __launch_bounds__(256) void pack_i8_fused_kernel(const int4* __restrict__ xsrc,
                                                            const int4* __restrict__ wsrc,
                                                            unsigned* __restrict__ xdst,
                                                            unsigned* __restrict__ wdst,
                                                            long nx4, long ntot4) {
    long i = (long)blockIdx.x * blockDim.x + threadIdx.x;
    if (i >= ntot4) return;
    const int4* src;
    unsigned* dst;
    long si;
    if (i < nx4) { src = xsrc; dst = xdst; si = i; }
    else         { src = wsrc; dst = wdst; si = i - nx4; }
    int4 a = src[si];
    dst[si] = (unsigned)((a.x & 0xff) | ((a.y & 0xff) << 8) |
                         ((a.z & 0xff) << 16) | (a.w << 24));
}

// C[m][n] = sum_k A[m][k]*B[n][k]  (both K-contiguous, int8), then
// out = clamp(round((acc + bias[n]) * (0.05*wscale[n]/0.1)), -128, 127) as int32.
//
// Single-barrier LDS double-buffer: per K-iter, stage tile k+1 into buf^1
// while computing tile k from buf; ONE __syncthreads per iter. The implicit
// vmcnt(0) drain at the barrier lands after all 16 MFMAs issued, so the
// staging loads overlap a full compute phase. Barrier count: 64 (was 128).
// NOTE: SQ_LDS_BANK_CONFLICT ~1.68e7 is fixed write-occupancy of
// global_load_lds_dwordx4 (8 cyc/issue), invariant across R3/R4/R5 — ignore.
__global__ __launch_bounds__(256) void qgemm_i8_kernel(const int8_t* __restrict__ A,
                                                       const int8_t* __restrict__ B,
                                                       const int* __restrict__ bias,
                                                       const float* __restrict__ wscale,
                                                       int* __restrict__ C) {
    __shared__ int8_t As[2][BM * BK];   // 2 x 8 KiB
    __shared__ int8_t Bs[2][BN * BK];   // 2 x 8 KiB

    const int tid  = threadIdx.x;
    const int wave = tid >> 6;
    const int lane = tid & 63;
    const int bm = blockIdx.y;
    const int bn = blockIdx.x;

    const int8_t* Ab = A + (size_t)bm * BM * K_DIM;
    const int8_t* Bb = B + (size_t)bn * BN * K_DIM;

    const int wm = wave >> 1;   // 0..1 : row half of tile
    const int wn = wave & 1;    // 0..1 : col half

    i32x4 acc[4][4] = {};       // 4x4 grid of 16x16 tiles (16 indep accumulators)

    // staging geometry: each wave-issue covers 16 rows x 64B = 1 KiB linear LDS
    const int srow = lane >> 2;          // 0..15
    const int scol = (lane & 3) * 16;    // 0/16/32/48

    // fragment geometry (mfma_i32_16x16x64_i8): m = lane&15, 16B/lane of K
    const int kq   = (lane >> 4) * 16;   // byte offset in 64B row
    const int mrow = wm * 64 + (lane & 15);
    const int nrow = wn * 64 + (lane & 15);

    auto stage = [&](int kt, int b) {
#pragma unroll
        for (int c = 0; c < 2; ++c) {
            const int g = c * 4 + wave;      // 0..7: 16-row block
            const size_t goff = (size_t)(g * 16 + srow) * K_DIM + kt + scol;
            async_load16(Ab + goff, &As[b][g * 1024]);
            async_load16(Bb + goff, &Bs[b][g * 1024]);
        }
    };

    auto compute = [&](int b) {
        i32x4 af[4], bf[4];
#pragma unroll
        for (int i = 0; i < 4; ++i)
            af[i] = *(const i32x4*)&As[b][(mrow + i * 16) * BK + kq];
#pragma unroll
        for (int j = 0; j < 4; ++j)
            bf[j] = *(const i32x4*)&Bs[b][(nrow + j * 16) * BK + kq];
#pragma unroll
        for (int i = 0; i < 4; ++i)
#pragma unroll
            for (int j = 0; j < 4; ++j)
                acc[i][j] = __builtin_amdgcn_mfma_i32_16x16x64_i8(
                    af[i], bf[j], acc[i][j], 0, 0, 0);
    };

    stage(0, 0);
    __syncthreads();

    // K_DIM/BK = 64 iterations, unrolled x2 so buffer indices are constants.
    for (int kt = 0; kt < K_DIM; kt += 2 * BK) {
        // phase 0: compute buf0, stage kt+BK -> buf1
        stage(kt + BK, 1);                 // kt+BK < K_DIM always (64 even iters)
        compute(0);
        __syncthreads();
        // phase 1: compute buf1, stage kt+2BK -> buf0
        const bool more = (kt + 2 * BK) < K_DIM;
        if (more) stage(kt + 2 * BK, 0);
        compute(1);
        if (more) __syncthreads();
    }

    // Epilogue. 16x16 C/D layout: col = lane&15, row = (lane>>4)*4 + reg
    const int col16 = lane & 15;
    const int rquad = (lane >> 4) * 4;
#pragma unroll
    for (int j = 0; j < 4; ++j) {
        const int col = bn * BN + wn * 64 + j * 16 + col16;
        float s = 0.05f * wscale[col];
        s = s / 0.1f;                      // match np ref arithmetic exactly
        const float bz = (float)bias[col];
#pragma unroll
        for (int i = 0; i < 4; ++i) {
            const int row0 = bm * BM + wm * 64 + i * 16 + rquad;
#pragma unroll
            for (int r = 0; r < 4; ++r) {
                float v = ((float)acc[i][j][r] + bz) * s;
                v = rintf(v);              // RTNE, matches np.round
                v = fminf(fmaxf(v, -128.0f), 127.0f);
                C[(size_t)(row0 + r) * N_DIM + col] = (int)v;
            }
        }
    }
}

extern "C" void kernel_launch(void* const* d_in, const int* in_sizes, int n_in,
                              void* d_out, int out_size, void* d_ws, size_t ws_size,
                              hipStream_t stream) {
    const int*   x32    = (const int*)d_in[0];     // int8 values promoted to int32
    const int*   w32    = (const int*)d_in[1];
    const int*   bias   = (const int*)d_in[2];
    const float* wscale = (const float*)d_in[3];
    int*         out    = (int*)d_out;

    int8_t* xp = (int8_t*)d_ws;                         // 32 MiB packed x
    int8_t* wp = xp + (size_t)M_DIM * K_DIM;            // 16 MiB packed w

    {
        long nx4   = (long)M_DIM * K_DIM / 4;
        long nw4   = (long)N_DIM * K_DIM / 4;
        long ntot4 = nx4 + nw4;
        pack_i8_fused_kernel<<<(int)((ntot4 + 255) / 256), 256, 0, stream>>>(
            (const int4*)x32, (const int4*)w32,
            (unsigned*)xp, (unsigned*)wp, nx4, ntot4);
    }

    dim3 grid(N_DIM / BN, M_DIM / BM);   // (32, 64)
    qgemm_i8_kernel<<<grid, 256, 0, stream>>>(xp, wp, bias, wscale, out);
}